// Round 3
// baseline (11243.275 us; speedup 1.0000x reference)
//
#include <hip/hip_runtime.h>
#include <cmath>

#define Mdim 32
#define Ndim 32
#define Tsteps 512
#define H1dim 5120
#define H2dim 4096
#define HIDdim 1000
#define NWG 256
#define NTHR 1024
#define POLLER 320   // wave 5 lane 0: no shadow-phase duties -> dedicated barrier poller
#define BAR_STRIDE 32  // dwords between arrival counters = 128B (one coherence granule)

typedef unsigned int u32;
typedef unsigned short u16;

// bf16 copies (filled by convert kernels each call)
__device__ u16 g_w2b[H2dim * HIDdim];        // [4096][1000]
__device__ u16 g_w3t[H2dim * Mdim * Ndim];   // transposed: [4096][1024]

// ---- LDS layout (bytes) ----
#define OFF_WIH 0          // 12 x 5120 bf16 = 122880
#define OFF_WHH 122880     // 12 x 1000 bf16 = 24000
#define OFF_UNION 146880   // 10240: s_x bf16[5120] | s_red4 f32x4[128] | s_pd f32[512]
#define OFF_H9 157120      // padded h: 125 chunks x 9 f32 = 4520
#define OFF_MISC 161640    // 216 floats
#define SMEM_BYTES 162560

#define MI_POST 0
#define MI_PRIOR 32
#define MI_INNOV 96
#define MI_KIN 128
#define MI_GI 192
#define MI_GH 204

__device__ __forceinline__ u16 f2bf(float f) {
  u32 u = __float_as_uint(f);
  return (u16)((u + 0x7fffu + ((u >> 16) & 1u)) >> 16);
}
__device__ __forceinline__ float bflo(u32 u) { return __uint_as_float(u << 16); }
__device__ __forceinline__ float bfhi(u32 u) { return __uint_as_float(u & 0xffff0000u); }

__device__ __forceinline__ float dot4(float4 a, float4 b) {
  return a.x * b.x + a.y * b.y + a.z * b.z + a.w * b.w;
}
__device__ __forceinline__ float dot8_bb(uint4 a, uint4 b) {
  float s = 0.f;
  s = fmaf(bflo(a.x), bflo(b.x), s); s = fmaf(bfhi(a.x), bfhi(b.x), s);
  s = fmaf(bflo(a.y), bflo(b.y), s); s = fmaf(bfhi(a.y), bfhi(b.y), s);
  s = fmaf(bflo(a.z), bflo(b.z), s); s = fmaf(bfhi(a.z), bfhi(b.z), s);
  s = fmaf(bflo(a.w), bflo(b.w), s); s = fmaf(bfhi(a.w), bfhi(b.w), s);
  return s;
}
__device__ __forceinline__ float dot8_bf(uint4 a, const float* x8) {
  float s = 0.f;
  s = fmaf(bflo(a.x), x8[0], s); s = fmaf(bfhi(a.x), x8[1], s);
  s = fmaf(bflo(a.y), x8[2], s); s = fmaf(bfhi(a.y), x8[3], s);
  s = fmaf(bflo(a.z), x8[4], s); s = fmaf(bfhi(a.z), x8[5], s);
  s = fmaf(bflo(a.w), x8[6], s); s = fmaf(bfhi(a.w), x8[7], s);
  return s;
}

__device__ __forceinline__ float wave_reduce64(float v) {
#pragma unroll
  for (int off = 32; off >= 1; off >>= 1) v += __shfl_xor(v, off, 64);
  return v;
}
__device__ __forceinline__ float group16_reduce(float v) {
#pragma unroll
  for (int off = 8; off >= 1; off >>= 1) v += __shfl_xor(v, off, 64);
  return v;
}

// ---- uncached (coherence-point) access helpers ----
__device__ __forceinline__ float4 ldg_cg4(const float* p) {
  float4 r;
  asm volatile("global_load_dwordx4 %0, %1, off sc0 sc1\n\ts_waitcnt vmcnt(0)"
               : "=v"(r) : "v"(p) : "memory");
  return r;
}
__device__ __forceinline__ uint4 ldg_cg4u(const void* p) {
  uint4 r;
  asm volatile("global_load_dwordx4 %0, %1, off sc0 sc1\n\ts_waitcnt vmcnt(0)"
               : "=v"(r) : "v"(p) : "memory");
  return r;
}
__device__ __forceinline__ void ldg2_cg4(const float* p0, const float* p1,
                                         float4& r0, float4& r1) {
  asm volatile("global_load_dwordx4 %0, %2, off sc0 sc1\n\t"
               "global_load_dwordx4 %1, %3, off sc0 sc1\n\t"
               "s_waitcnt vmcnt(0)"
               : "=&v"(r0), "=&v"(r1) : "v"(p0), "v"(p1) : "memory");
}
__device__ __forceinline__ void stg_cg1(float* p, float v) {
  asm volatile("global_store_dword %0, %1, off sc0 sc1" :: "v"(p), "v"(v) : "memory");
}
__device__ __forceinline__ void stg_cg_u16(u16* p, u16 v) {
  u32 vv = v;
  asm volatile("global_store_short %0, %1, off sc0 sc1" :: "v"(p), "v"(vv) : "memory");
}

// ---- one-hop grid barrier: 16 arrival counters (16 WGs each, 128B apart);
// pollers read+sum all 16 (monotone counters -> undercount-safe). Removes the
// two chained RMW hops of the old tree: post-last-arrival = 1 RMW + 1 poll round.
__device__ __forceinline__ void gb_arrive(u32* bar) {
  asm volatile("s_waitcnt vmcnt(0)" ::: "memory");
  __syncthreads();
  if (threadIdx.x == POLLER)
    __hip_atomic_fetch_add(bar + ((u32)blockIdx.x & 15u) * BAR_STRIDE, 1u,
                           __ATOMIC_RELAXED, __HIP_MEMORY_SCOPE_AGENT);
}
__device__ __forceinline__ void gb_wait(u32* bar, u32 nb) {
  if (threadIdx.x == POLLER) {
    const u32 target = nb * (u32)NWG;
    for (;;) {
      u32 s = 0;
#pragma unroll
      for (int g = 0; g < 16; ++g)
        s += __hip_atomic_load(bar + g * BAR_STRIDE, __ATOMIC_RELAXED,
                               __HIP_MEMORY_SCOPE_AGENT);
      if (s >= target) break;
      __builtin_amdgcn_s_sleep(1);
    }
  }
  __syncthreads();
}

__global__ void convert_w2(const float* __restrict__ W2) {
  int i = blockIdx.x * 1024 + threadIdx.x;
  if (i < H2dim * HIDdim) g_w2b[i] = f2bf(W2[i]);
}

__global__ void convert_w3t(const float* __restrict__ W3) {
  __shared__ float tile[32][33];
  int tr = blockIdx.x >> 7;    // 0..31
  int tc = blockIdx.x & 127;   // 0..127
  int r0 = tr * 32, c0 = tc * 32;
  int j = threadIdx.x & 31, i0 = threadIdx.x >> 5;
#pragma unroll
  for (int p = 0; p < 4; ++p) {
    int i = i0 + p * 8;
    tile[i][j] = W3[(size_t)(r0 + i) * H2dim + c0 + j];
  }
  __syncthreads();
#pragma unroll
  for (int p = 0; p < 4; ++p) {
    int i = i0 + p * 8;
    g_w3t[(size_t)(c0 + i) * 1024 + r0 + j] = f2bf(tile[j][i]);
  }
}

// amdgpu_waves_per_eu(4,4): occupancy is hard-capped at 4 waves/EU by the
// 158.75KB dynamic LDS (1 WG/CU); pin the allocator's target there so the
// VGPR cap is 128 and the step-invariant fragments stay resident.
// (R1/R2's __launch_bounds__(,4) did NOT move VGPR_Count off 64; spill showed
// as +20MB WRITE_SIZE.)
__attribute__((amdgpu_waves_per_eu(4, 4)))
__global__ void __launch_bounds__(NTHR)
knet_kernel(const float* __restrict__ y, const float* __restrict__ F,
            const float* __restrict__ Hm, const float* __restrict__ m1x0,
            const float* __restrict__ h0, const float* __restrict__ W1,
            const float* __restrict__ b1, const float* __restrict__ Wih,
            const float* __restrict__ bih, const float* __restrict__ Whh,
            const float* __restrict__ bhh, const float* __restrict__ b2,
            const float* __restrict__ b3, float* __restrict__ out,
            u32* bar, u16* xb, float* hbuf, float* dpart) {
  extern __shared__ char smem[];
  u16* s_wih = (u16*)(smem + OFF_WIH);
  u16* s_whh = (u16*)(smem + OFF_WHH);
  u16* s_x = (u16*)(smem + OFF_UNION);
  float4* s_red4 = (float4*)(smem + OFF_UNION);
  float* s_redf = (float*)(smem + OFF_UNION);
  float* s_pd = (float*)(smem + OFF_UNION);
  float* s_h9 = (float*)(smem + OFF_H9);
  float* s_m = (float*)(smem + OFF_MISC);
  float* s_post = s_m + MI_POST;
  float* s_prior = s_m + MI_PRIOR;
  float* s_innov = s_m + MI_INNOV;
  float* s_kin = s_m + MI_KIN;
  float* s_gi = s_m + MI_GI;
  float* s_gh = s_m + MI_GH;

  const int tid = threadIdx.x;
  const int w = tid >> 6;
  const int lane = tid & 63;
  const int wg = blockIdx.x;
  const int k0 = wg * 4;
  const bool gru_wg = (wg < 250);
  u32 nb = 0;

  // ---------------- prologue: LDS weight staging ----------------
  if (gru_wg) {
#pragma unroll 1
    for (int r = 0; r < 12; ++r) {
      const float* src = Wih + (size_t)((r >> 2) * HIDdim + k0 + (r & 3)) * H1dim;
      u16* dst = s_wih + r * H1dim;
      for (int e = tid; e < H1dim; e += NTHR) dst[e] = f2bf(src[e]);
    }
#pragma unroll 1
    for (int r = 0; r < 12; ++r) {
      const float* src = Whh + (size_t)((r >> 2) * HIDdim + k0 + (r & 3)) * HIDdim;
      u16* dst = s_whh + r * HIDdim;
      for (int e = tid; e < HIDdim; e += NTHR) dst[e] = f2bf(src[e]);
    }
  }
  if (tid < 250) {
    float4 hv = ((const float4*)h0)[tid];
    int b0 = tid * 4;
    s_h9[((b0 + 0) >> 3) * 9 + ((b0 + 0) & 7)] = hv.x;
    s_h9[((b0 + 1) >> 3) * 9 + ((b0 + 1) & 7)] = hv.y;
    s_h9[((b0 + 2) >> 3) * 9 + ((b0 + 2) & 7)] = hv.z;
    s_h9[((b0 + 3) >> 3) * 9 + ((b0 + 3) & 7)] = hv.w;
  }
  __syncthreads();

  // ---------------- step-invariant per-thread register constants ----------------
  // Phase C row slices (W2 row c2, W3t row c2) are the same every step.
  const int c2 = wg * 16 + w;
  const uint4* w2p = (const uint4*)(g_w2b + (size_t)c2 * HIDdim);
  uint4 wr0r = w2p[lane];
  uint4 wr1r = make_uint4(0u, 0u, 0u, 0u);
  if (lane < 61) wr1r = w2p[lane + 64];
  const uint4* w3p = (const uint4*)(g_w3t + (size_t)c2 * 1024);
  uint4 t0r = w3p[2 * lane];
  uint4 t1r = w3p[2 * lane + 1];
  const float b2c = b2[c2];
  // W1 row fragment (w<5): one float4 + bias per thread, constant across steps.
  float4 w1c = make_float4(0.f, 0.f, 0.f, 0.f);
  float b1c = 0.f;
  int w1row = 0;
  if (w < 5) {
    w1row = wg * 20 + w * 4 + (lane >> 4);
    w1c = ((const float4*)W1)[w1row * 16 + (lane & 15)];
    b1c = b1[w1row];
  }
  // wave-0 persistent state: prior (lanes<32), prefetched y row, b3·innov term
  float prior = 0.f, bb = 0.f, yv = 0.f;
  if (w == 0 && lane < 32) {
    prior = m1x0[lane];
    yv = y[lane];  // y row 0
  }

  // gh for t=0: Whh @ h0 (needs staged s_whh/s_h9, synced above)
  auto gh_compute = [&]() {
    int base = (w - 12) * 3;
#pragma unroll
    for (int rr = 0; rr < 3; ++rr) {
      int r = base + rr;
      const uint4* wr = (const uint4*)(s_whh + r * HIDdim);
      float acc = dot8_bf(wr[lane], s_h9 + lane * 9);
      if (lane < 61) acc += dot8_bf(wr[lane + 64], s_h9 + (lane + 64) * 9);
      acc = wave_reduce64(acc);
      if (lane == 0) s_gh[r] = acc + bhh[(r >> 2) * HIDdim + k0 + (r & 3)];
    }
  };
  if (gru_wg && w >= 12) gh_compute();

  for (int t = 0; t < Tsteps; ++t) {
    // ---------------- Phase A ----------------
    if (t > 0) {  // gather delta partials: 2048 float4, 2 per thread
      float4 a0, a1;
      ldg2_cg4(dpart + tid * 4, dpart + (tid + 1024) * 4, a0, a1);
      float4 s;
      s.x = a0.x + a1.x; s.y = a0.y + a1.y; s.z = a0.z + a1.z; s.w = a0.w + a1.w;
#pragma unroll
      for (int off = 8; off <= 32; off <<= 1) {
        s.x += __shfl_xor(s.x, off, 64);
        s.y += __shfl_xor(s.y, off, 64);
        s.z += __shfl_xor(s.z, off, 64);
        s.w += __shfl_xor(s.w, off, 64);
      }
      if (lane < 8) s_red4[w * 8 + lane] = s;
    }
    __syncthreads();
    // merged serial chain, wave 0 only: no interior __syncthreads (same-wave LDS
    // is in-order; compiler-only fences stop reordering of f32 vs float4 views).
    if (w == 0) {
      float p = 0.f, inn = 0.f;
      float prev = prior;
      if (lane < 32) {
        if (t == 0) {
          p = m1x0[lane];
        } else {
          float dsum = 0.f;
#pragma unroll
          for (int ww = 0; ww < 16; ++ww) dsum += s_redf[ww * 32 + lane];
          p = prior + dsum + bb;  // bb = b3·innov computed in last S3 shadow
          if (wg == 0) out[(t - 1) * Mdim + lane] = p;
        }
        s_post[lane] = p;
      }
      asm volatile("" ::: "memory");
      if (lane < 32) {  // prior = F @ post
        const float4* Fr = (const float4*)(F + lane * Mdim);
        const float4* pp = (const float4*)s_post;
        float s = 0.f;
#pragma unroll
        for (int j = 0; j < 8; ++j) s += dot4(Fr[j], pp[j]);
        prior = s;
        s_prior[lane] = s;
      }
      asm volatile("" ::: "memory");
      if (lane < 32) {  // innov = y_t - H @ prior
        const float4* Hr = (const float4*)(Hm + lane * Mdim);
        const float4* pp = (const float4*)s_prior;
        float s = 0.f;
#pragma unroll
        for (int j = 0; j < 8; ++j) s += dot4(Hr[j], pp[j]);
        inn = yv - s;  // yv prefetched in S3 shadow
        s_innov[lane] = inn;
      }
      // kin: lanes<32 innov, lanes>=32 (post - prev_prior); normalize halves
      float vd = __shfl(p, lane & 31, 64) - __shfl(prev, lane & 31, 64);
      float v = (lane < 32) ? inn : vd;
      float sq = v * v;
#pragma unroll
      for (int off = 16; off >= 1; off >>= 1) sq += __shfl_xor(sq, off, 32);
      s_kin[lane] = v / fmaxf(sqrtf(sq), 1e-12f);
    }
    __syncthreads();
    if (w < 5) {  // x rows: 20/WG, W1 fragment held in registers
      float s = dot4(w1c, ((const float4*)s_kin)[lane & 15]);
      s = group16_reduce(s);
      if ((lane & 15) == 0) stg_cg_u16(xb + w1row, f2bf(fmaxf(s + b1c, 0.f)));
    }
    ++nb;
    gb_arrive(bar);              // S1: x ready
    gb_wait(bar, nb);

    // ---------------- Phase B: gi + gates -> h ----------------
    if (gru_wg) {
      if (tid < 640) ((uint4*)s_x)[tid] = ldg_cg4u((const char*)xb + tid * 16);
      __syncthreads();
      if (w < 12) {
        const uint4* wr = (const uint4*)(s_wih + w * H1dim);
        const uint4* xr = (const uint4*)s_x;
        float acc = 0.f;
#pragma unroll
        for (int i = 0; i < 10; ++i) {
          int j = lane + 64 * i;
          acc += dot8_bb(wr[j], xr[j]);
        }
        acc = wave_reduce64(acc);
        if (lane == 0) s_gi[w] = acc + bih[(w >> 2) * HIDdim + k0 + (w & 3)];
      }
      __syncthreads();
      if (tid < 4) {
        int k = k0 + tid;
        float hold = s_h9[(k >> 3) * 9 + (k & 7)];
        float ir = s_gi[tid], iz = s_gi[4 + tid], ic = s_gi[8 + tid];
        float r = 1.f / (1.f + expf(-(ir + s_gh[tid])));
        float z = 1.f / (1.f + expf(-(iz + s_gh[4 + tid])));
        float c_ = tanhf(ic + r * s_gh[8 + tid]);
        stg_cg1(hbuf + k, (1.f - z) * c_ + z * hold);
      }
    }
    ++nb;
    gb_arrive(bar);              // S2: h ready
    // S2 shadow: u = W3t row · innov (independent of h; W3t row in registers)
    float u;
    {
      const float* iv = s_innov + 16 * (lane & 1);
      u = dot8_bf(t0r, iv) + dot8_bf(t1r, iv + 8);
      u += __shfl_xor(u, 1, 64);
    }
    gb_wait(bar, nb);

    // ---------------- Phase C: l2 rows + delta partials ----------------
    if (tid < 250) {  // stage h_t (padded)
      float4 hv = ldg_cg4(hbuf + tid * 4);
      int b0 = tid * 4;
      s_h9[((b0 + 0) >> 3) * 9 + ((b0 + 0) & 7)] = hv.x;
      s_h9[((b0 + 1) >> 3) * 9 + ((b0 + 1) & 7)] = hv.y;
      s_h9[((b0 + 2) >> 3) * 9 + ((b0 + 2) & 7)] = hv.z;
      s_h9[((b0 + 3) >> 3) * 9 + ((b0 + 3) & 7)] = hv.w;
    }
    __syncthreads();
    {
      float acc = dot8_bf(wr0r, s_h9 + lane * 9);
      if (lane < 61) acc += dot8_bf(wr1r, s_h9 + (lane + 64) * 9);
      acc = wave_reduce64(acc);
      float l2c = fmaxf(acc + b2c, 0.f);
      if ((lane & 1) == 0) s_pd[w * 32 + (lane >> 1)] = l2c * u;
    }
    __syncthreads();
    if (tid < 32) {
      float pdv = 0.f;
#pragma unroll
      for (int ww = 0; ww < 16; ++ww) pdv += s_pd[ww * 32 + tid];
      stg_cg1(dpart + wg * 32 + tid, pdv);
    }
    ++nb;
    gb_arrive(bar);              // S3: delta partials ready
    // S3 shadow: next step's gh (Whh@h_t), b3·innov_t, y[t+1] prefetch
    if (gru_wg && w >= 12) gh_compute();
    if (w == 0 && lane < 32) {
      int tn = (t + 1 < Tsteps) ? t + 1 : Tsteps - 1;
      yv = y[tn * Ndim + lane];
      float b = 0.f;
#pragma unroll 8
      for (int j = 0; j < 32; ++j) b = fmaf(b3[lane * 32 + j], s_innov[j], b);
      bb = b;
    }
    gb_wait(bar, nb);
  }

  // ---------------- epilogue: out row 511 ----------------
  if (wg == 0) {
    float4 a0, a1;
    ldg2_cg4(dpart + tid * 4, dpart + (tid + 1024) * 4, a0, a1);
    float4 s;
    s.x = a0.x + a1.x; s.y = a0.y + a1.y; s.z = a0.z + a1.z; s.w = a0.w + a1.w;
#pragma unroll
    for (int off = 8; off <= 32; off <<= 1) {
      s.x += __shfl_xor(s.x, off, 64);
      s.y += __shfl_xor(s.y, off, 64);
      s.z += __shfl_xor(s.z, off, 64);
      s.w += __shfl_xor(s.w, off, 64);
    }
    if (lane < 8) s_red4[w * 8 + lane] = s;
    __syncthreads();
    if (w == 0 && lane < 32) {
      float d = 0.f;
#pragma unroll
      for (int ww = 0; ww < 16; ++ww) d += s_redf[ww * 32 + lane];
      out[(Tsteps - 1) * Mdim + lane] = prior + d + bb;  // bb from last S3 shadow
    }
  }
}

extern "C" void kernel_launch(void* const* d_in, const int* in_sizes, int n_in,
                              void* d_out, int out_size, void* d_ws, size_t ws_size,
                              hipStream_t stream) {
  const float* y    = (const float*)d_in[0];
  const float* F    = (const float*)d_in[1];
  const float* Hm   = (const float*)d_in[2];
  const float* m1x0 = (const float*)d_in[3];
  const float* h0   = (const float*)d_in[4];
  const float* W1   = (const float*)d_in[5];
  const float* b1   = (const float*)d_in[6];
  const float* Wih  = (const float*)d_in[7];
  const float* bih  = (const float*)d_in[8];
  const float* Whh  = (const float*)d_in[9];
  const float* bhh  = (const float*)d_in[10];
  const float* W2   = (const float*)d_in[11];
  const float* b2   = (const float*)d_in[12];
  const float* W3   = (const float*)d_in[13];
  const float* b3   = (const float*)d_in[14];
  float* out = (float*)d_out;

  // ws layout: bar[0,4096); xb@4096 (10240B); hbuf@14336 (4000B); dpart@18432 (32768B)
  u32* bar   = (u32*)d_ws;
  u16* xb    = (u16*)((char*)d_ws + 4096);
  float* hbuf  = (float*)((char*)d_ws + 14336);
  float* dpart = (float*)((char*)d_ws + 18432);

  convert_w2<<<4000, 1024, 0, stream>>>(W2);
  convert_w3t<<<4096, 256, 0, stream>>>(W3);
  hipMemsetAsync(d_ws, 0, 4096, stream);
  hipFuncSetAttribute((const void*)knet_kernel,
                      hipFuncAttributeMaxDynamicSharedMemorySize, SMEM_BYTES);
  void* args[] = {&y, &F, &Hm, &m1x0, &h0, &W1, &b1, &Wih, &bih, &Whh, &bhh,
                  &b2, &b3, &out, &bar, &xb, &hbuf, &dpart};
  hipLaunchCooperativeKernel((const void*)knet_kernel, dim3(NWG), dim3(NTHR),
                             args, SMEM_BYTES, stream);
}

// Round 4
// 7458.060 us; speedup vs baseline: 1.5075x; 1.5075x over previous
//
#include <hip/hip_runtime.h>
#include <cmath>

#define Mdim 32
#define Ndim 32
#define Tsteps 512
#define H1dim 5120
#define H2dim 4096
#define HIDdim 1000
#define NWG 256
#define NTHR 1024
#define POLLER 320   // wave 5 lane 0: no shadow-phase duties -> dedicated barrier poller

typedef unsigned int u32;
typedef unsigned short u16;

// bf16 copies (filled by convert kernels each call)
__device__ u16 g_w2b[H2dim * HIDdim];        // [4096][1000]
__device__ u16 g_w3t[H2dim * Mdim * Ndim];   // transposed: [4096][1024]

// ---- LDS layout (bytes) ----
#define OFF_WIH 0          // 12 x 5120 bf16 = 122880
#define OFF_WHH 122880     // 12 x 1000 bf16 = 24000
#define OFF_UNION 146880   // 10240: s_x bf16[5120] | s_red4 f32x4[128] | s_pd f32[512]
#define OFF_H9 157120      // padded h: 125 chunks x 9 f32 = 4520
#define OFF_MISC 161640    // 216 floats
#define SMEM_BYTES 162560

#define MI_POST 0
#define MI_PRIOR 32
#define MI_INNOV 96
#define MI_KIN 128
#define MI_GI 192
#define MI_GH 204

__device__ __forceinline__ u16 f2bf(float f) {
  u32 u = __float_as_uint(f);
  return (u16)((u + 0x7fffu + ((u >> 16) & 1u)) >> 16);
}
__device__ __forceinline__ float bflo(u32 u) { return __uint_as_float(u << 16); }
__device__ __forceinline__ float bfhi(u32 u) { return __uint_as_float(u & 0xffff0000u); }

__device__ __forceinline__ float dot4(float4 a, float4 b) {
  return a.x * b.x + a.y * b.y + a.z * b.z + a.w * b.w;
}
__device__ __forceinline__ float dot8_bb(uint4 a, uint4 b) {
  float s = 0.f;
  s = fmaf(bflo(a.x), bflo(b.x), s); s = fmaf(bfhi(a.x), bfhi(b.x), s);
  s = fmaf(bflo(a.y), bflo(b.y), s); s = fmaf(bfhi(a.y), bfhi(b.y), s);
  s = fmaf(bflo(a.z), bflo(b.z), s); s = fmaf(bfhi(a.z), bfhi(b.z), s);
  s = fmaf(bflo(a.w), bflo(b.w), s); s = fmaf(bfhi(a.w), bfhi(b.w), s);
  return s;
}
__device__ __forceinline__ float dot8_bf(uint4 a, const float* x8) {
  float s = 0.f;
  s = fmaf(bflo(a.x), x8[0], s); s = fmaf(bfhi(a.x), x8[1], s);
  s = fmaf(bflo(a.y), x8[2], s); s = fmaf(bfhi(a.y), x8[3], s);
  s = fmaf(bflo(a.z), x8[4], s); s = fmaf(bfhi(a.z), x8[5], s);
  s = fmaf(bflo(a.w), x8[6], s); s = fmaf(bfhi(a.w), x8[7], s);
  return s;
}

__device__ __forceinline__ float wave_reduce64(float v) {
#pragma unroll
  for (int off = 32; off >= 1; off >>= 1) v += __shfl_xor(v, off, 64);
  return v;
}
__device__ __forceinline__ float group16_reduce(float v) {
#pragma unroll
  for (int off = 8; off >= 1; off >>= 1) v += __shfl_xor(v, off, 64);
  return v;
}

// ---- uncached (coherence-point) access helpers ----
__device__ __forceinline__ float4 ldg_cg4(const float* p) {
  float4 r;
  asm volatile("global_load_dwordx4 %0, %1, off sc0 sc1\n\ts_waitcnt vmcnt(0)"
               : "=v"(r) : "v"(p) : "memory");
  return r;
}
__device__ __forceinline__ uint4 ldg_cg4u(const void* p) {
  uint4 r;
  asm volatile("global_load_dwordx4 %0, %1, off sc0 sc1\n\ts_waitcnt vmcnt(0)"
               : "=v"(r) : "v"(p) : "memory");
  return r;
}
__device__ __forceinline__ void ldg2_cg4(const float* p0, const float* p1,
                                         float4& r0, float4& r1) {
  asm volatile("global_load_dwordx4 %0, %2, off sc0 sc1\n\t"
               "global_load_dwordx4 %1, %3, off sc0 sc1\n\t"
               "s_waitcnt vmcnt(0)"
               : "=&v"(r0), "=&v"(r1) : "v"(p0), "v"(p1) : "memory");
}
__device__ __forceinline__ void stg_cg1(float* p, float v) {
  asm volatile("global_store_dword %0, %1, off sc0 sc1" :: "v"(p), "v"(v) : "memory");
}
__device__ __forceinline__ void stg_cg_u16(u16* p, u16 v) {
  u32 vv = v;
  asm volatile("global_store_short %0, %1, off sc0 sc1" :: "v"(p), "v"(vv) : "memory");
}

// ---- two-hop grid barrier: 16 arrival counters (16 WGs each; <=16 writers/line,
// proven safe) -> last-in-group escalates DIRECTLY to one go-accumulator.
// go advances by 16 per barrier; pollers watch exactly ONE line (R3 lesson).
// Split arrive/wait so independent work hides under barrier latency.
__device__ __forceinline__ void gb_arrive(u32* bar) {
  asm volatile("s_waitcnt vmcnt(0)" ::: "memory");
  __syncthreads();
  if (threadIdx.x == POLLER) {
    u32 g = (u32)blockIdx.x & 15u;
    u32 a = __hip_atomic_fetch_add(bar + g * 16, 1u, __ATOMIC_RELAXED,
                                   __HIP_MEMORY_SCOPE_AGENT);
    if ((a & 15u) == 15u)
      __hip_atomic_fetch_add(bar + 320, 1u, __ATOMIC_RELAXED,
                             __HIP_MEMORY_SCOPE_AGENT);
  }
}
__device__ __forceinline__ void gb_wait(u32* bar, u32 nb) {
  if (threadIdx.x == POLLER) {
    const u32 target = nb * 16u;
    while (__hip_atomic_load(bar + 320, __ATOMIC_RELAXED,
                             __HIP_MEMORY_SCOPE_AGENT) < target)
      __builtin_amdgcn_s_sleep(2);
  }
  __syncthreads();
}

__global__ void convert_w2(const float* __restrict__ W2) {
  int i = blockIdx.x * 1024 + threadIdx.x;
  if (i < H2dim * HIDdim) g_w2b[i] = f2bf(W2[i]);
}

__global__ void convert_w3t(const float* __restrict__ W3) {
  __shared__ float tile[32][33];
  int tr = blockIdx.x >> 7;    // 0..31
  int tc = blockIdx.x & 127;   // 0..127
  int r0 = tr * 32, c0 = tc * 32;
  int j = threadIdx.x & 31, i0 = threadIdx.x >> 5;
#pragma unroll
  for (int p = 0; p < 4; ++p) {
    int i = i0 + p * 8;
    tile[i][j] = W3[(size_t)(r0 + i) * H2dim + c0 + j];
  }
  __syncthreads();
#pragma unroll
  for (int p = 0; p < 4; ++p) {
    int i = i0 + p * 8;
    g_w3t[(size_t)(c0 + i) * 1024 + r0 + j] = f2bf(tile[j][i]);
  }
}

// NOTE: no loop-carried weight hoists. R1-R3 proved the allocator pins 64 VGPR
// for 1024-thread blocks and spills them to scratch (+20MB WRITE_SIZE).
// Weights are re-loaded in-loop (L1/L2-resident) or prefetched into
// short-lived registers inside the barrier shadows.
__global__ void __launch_bounds__(NTHR)
knet_kernel(const float* __restrict__ y, const float* __restrict__ F,
            const float* __restrict__ Hm, const float* __restrict__ m1x0,
            const float* __restrict__ h0, const float* __restrict__ W1,
            const float* __restrict__ b1, const float* __restrict__ Wih,
            const float* __restrict__ bih, const float* __restrict__ Whh,
            const float* __restrict__ bhh, const float* __restrict__ b2,
            const float* __restrict__ b3, float* __restrict__ out,
            u32* bar, u16* xb, float* hbuf, float* dpart) {
  extern __shared__ char smem[];
  u16* s_wih = (u16*)(smem + OFF_WIH);
  u16* s_whh = (u16*)(smem + OFF_WHH);
  u16* s_x = (u16*)(smem + OFF_UNION);
  float4* s_red4 = (float4*)(smem + OFF_UNION);
  float* s_redf = (float*)(smem + OFF_UNION);
  float* s_pd = (float*)(smem + OFF_UNION);
  float* s_h9 = (float*)(smem + OFF_H9);
  float* s_m = (float*)(smem + OFF_MISC);
  float* s_post = s_m + MI_POST;
  float* s_prior = s_m + MI_PRIOR;
  float* s_innov = s_m + MI_INNOV;
  float* s_kin = s_m + MI_KIN;
  float* s_gi = s_m + MI_GI;
  float* s_gh = s_m + MI_GH;

  const int tid = threadIdx.x;
  const int w = tid >> 6;
  const int lane = tid & 63;
  const int wg = blockIdx.x;
  const int k0 = wg * 4;
  const bool gru_wg = (wg < 250);
  u32 nb = 0;

  // ---------------- prologue: LDS weight staging ----------------
  if (gru_wg) {
#pragma unroll 1
    for (int r = 0; r < 12; ++r) {
      const float* src = Wih + (size_t)((r >> 2) * HIDdim + k0 + (r & 3)) * H1dim;
      u16* dst = s_wih + r * H1dim;
      for (int e = tid; e < H1dim; e += NTHR) dst[e] = f2bf(src[e]);
    }
#pragma unroll 1
    for (int r = 0; r < 12; ++r) {
      const float* src = Whh + (size_t)((r >> 2) * HIDdim + k0 + (r & 3)) * HIDdim;
      u16* dst = s_whh + r * HIDdim;
      for (int e = tid; e < HIDdim; e += NTHR) dst[e] = f2bf(src[e]);
    }
  }
  if (tid < 250) {
    float4 hv = ((const float4*)h0)[tid];
    int b0 = tid * 4;
    s_h9[((b0 + 0) >> 3) * 9 + ((b0 + 0) & 7)] = hv.x;
    s_h9[((b0 + 1) >> 3) * 9 + ((b0 + 1) & 7)] = hv.y;
    s_h9[((b0 + 2) >> 3) * 9 + ((b0 + 2) & 7)] = hv.z;
    s_h9[((b0 + 3) >> 3) * 9 + ((b0 + 3) & 7)] = hv.w;
  }
  __syncthreads();

  const int c2 = wg * 16 + w;            // this wave's W2/W3t row
  const int w1row = wg * 20 + w * 4 + (lane >> 4);  // valid for w<5
  // wave-0 persistent state: prior (lanes<32), prefetched y row, b3·innov term
  float prior = 0.f, bb = 0.f, yv = 0.f;
  if (w == 0 && lane < 32) {
    prior = m1x0[lane];
    yv = y[lane];  // y row 0
  }

  // gh: Whh @ h (needs staged s_whh/s_h9)
  auto gh_compute = [&]() {
    int base = (w - 12) * 3;
#pragma unroll
    for (int rr = 0; rr < 3; ++rr) {
      int r = base + rr;
      const uint4* wr = (const uint4*)(s_whh + r * HIDdim);
      float acc = dot8_bf(wr[lane], s_h9 + lane * 9);
      if (lane < 61) acc += dot8_bf(wr[lane + 64], s_h9 + (lane + 64) * 9);
      acc = wave_reduce64(acc);
      if (lane == 0) s_gh[r] = acc + bhh[(r >> 2) * HIDdim + k0 + (r & 3)];
    }
  };
  if (gru_wg && w >= 12) gh_compute();

  for (int t = 0; t < Tsteps; ++t) {
    // ---------------- Phase A ----------------
    if (t > 0) {  // gather delta partials: 2048 float4, 2 per thread
      float4 a0, a1;
      ldg2_cg4(dpart + tid * 4, dpart + (tid + 1024) * 4, a0, a1);
      float4 s;
      s.x = a0.x + a1.x; s.y = a0.y + a1.y; s.z = a0.z + a1.z; s.w = a0.w + a1.w;
#pragma unroll
      for (int off = 8; off <= 32; off <<= 1) {
        s.x += __shfl_xor(s.x, off, 64);
        s.y += __shfl_xor(s.y, off, 64);
        s.z += __shfl_xor(s.z, off, 64);
        s.w += __shfl_xor(s.w, off, 64);
      }
      if (lane < 8) s_red4[w * 8 + lane] = s;
    }
    __syncthreads();
    // merged serial chain, wave 0 only: no interior __syncthreads (same-wave LDS
    // is in-order; compiler-only fences stop reordering of f32 vs float4 views).
    if (w == 0) {
      float p = 0.f, inn = 0.f;
      float prev = prior;
      if (lane < 32) {
        if (t == 0) {
          p = m1x0[lane];
        } else {
          float dsum = 0.f;
#pragma unroll
          for (int ww = 0; ww < 16; ++ww) dsum += s_redf[ww * 32 + lane];
          p = prior + dsum + bb;  // bb = b3·innov computed in last S3 shadow
          if (wg == 0) out[(t - 1) * Mdim + lane] = p;
        }
        s_post[lane] = p;
      }
      asm volatile("" ::: "memory");
      if (lane < 32) {  // prior = F @ post
        const float4* Fr = (const float4*)(F + lane * Mdim);
        const float4* pp = (const float4*)s_post;
        float s = 0.f;
#pragma unroll
        for (int j = 0; j < 8; ++j) s += dot4(Fr[j], pp[j]);
        prior = s;
        s_prior[lane] = s;
      }
      asm volatile("" ::: "memory");
      if (lane < 32) {  // innov = y_t - H @ prior
        const float4* Hr = (const float4*)(Hm + lane * Mdim);
        const float4* pp = (const float4*)s_prior;
        float s = 0.f;
#pragma unroll
        for (int j = 0; j < 8; ++j) s += dot4(Hr[j], pp[j]);
        inn = yv - s;  // yv prefetched in S3 shadow
        s_innov[lane] = inn;
      }
      // kin: lanes<32 innov, lanes>=32 (post - prev_prior); normalize halves
      float vd = __shfl(p, lane & 31, 64) - __shfl(prev, lane & 31, 64);
      float v = (lane < 32) ? inn : vd;
      float sq = v * v;
#pragma unroll
      for (int off = 16; off >= 1; off >>= 1) sq += __shfl_xor(sq, off, 32);
      s_kin[lane] = v / fmaxf(sqrtf(sq), 1e-12f);
    }
    __syncthreads();
    if (w < 5) {  // x rows: 20/WG (W1 row slice is L1-resident: 5KB/WG)
      float s = dot4(((const float4*)W1)[w1row * 16 + (lane & 15)],
                     ((const float4*)s_kin)[lane & 15]);
      s = group16_reduce(s);
      if ((lane & 15) == 0) stg_cg_u16(xb + w1row, f2bf(fmaxf(s + b1[w1row], 0.f)));
    }
    ++nb;
    gb_arrive(bar);              // S1: x ready
    gb_wait(bar, nb);

    // ---------------- Phase B: gi + gates -> h ----------------
    if (gru_wg) {
      if (tid < 640) ((uint4*)s_x)[tid] = ldg_cg4u((const char*)xb + tid * 16);
      __syncthreads();
      if (w < 12) {
        const uint4* wr = (const uint4*)(s_wih + w * H1dim);
        const uint4* xr = (const uint4*)s_x;
        float acc = 0.f;
#pragma unroll
        for (int i = 0; i < 10; ++i) {
          int j = lane + 64 * i;
          acc += dot8_bb(wr[j], xr[j]);
        }
        acc = wave_reduce64(acc);
        if (lane == 0) s_gi[w] = acc + bih[(w >> 2) * HIDdim + k0 + (w & 3)];
      }
      __syncthreads();
      if (tid < 4) {
        int k = k0 + tid;
        float hold = s_h9[(k >> 3) * 9 + (k & 7)];
        float ir = s_gi[tid], iz = s_gi[4 + tid], ic = s_gi[8 + tid];
        float r = 1.f / (1.f + expf(-(ir + s_gh[tid])));
        float z = 1.f / (1.f + expf(-(iz + s_gh[4 + tid])));
        float c_ = tanhf(ic + r * s_gh[8 + tid]);
        stg_cg1(hbuf + k, (1.f - z) * c_ + z * hold);
      }
    }
    ++nb;
    gb_arrive(bar);              // S2: h ready
    // S2 shadow (short register lifetimes only — spans gb_wait, not the loop):
    //   u = W3t row · innov (independent of h), and prefetch this wave's W2 row.
    float u;
    uint4 w2a, w2b_;
    {
      const uint4* tr3 = (const uint4*)(g_w3t + (size_t)c2 * 1024);
      uint4 t0 = tr3[2 * lane], t1 = tr3[2 * lane + 1];
      const float* iv = s_innov + 16 * (lane & 1);
      u = dot8_bf(t0, iv) + dot8_bf(t1, iv + 8);
      u += __shfl_xor(u, 1, 64);
      const uint4* w2p = (const uint4*)(g_w2b + (size_t)c2 * HIDdim);
      w2a = w2p[lane];
      w2b_ = (lane < 61) ? w2p[lane + 64] : make_uint4(0u, 0u, 0u, 0u);
    }
    gb_wait(bar, nb);

    // ---------------- Phase C: l2 rows + delta partials ----------------
    if (tid < 250) {  // stage h_t (padded)
      float4 hv = ldg_cg4(hbuf + tid * 4);
      int b0 = tid * 4;
      s_h9[((b0 + 0) >> 3) * 9 + ((b0 + 0) & 7)] = hv.x;
      s_h9[((b0 + 1) >> 3) * 9 + ((b0 + 1) & 7)] = hv.y;
      s_h9[((b0 + 2) >> 3) * 9 + ((b0 + 2) & 7)] = hv.z;
      s_h9[((b0 + 3) >> 3) * 9 + ((b0 + 3) & 7)] = hv.w;
    }
    __syncthreads();
    {
      float acc = dot8_bf(w2a, s_h9 + lane * 9);
      if (lane < 61) acc += dot8_bf(w2b_, s_h9 + (lane + 64) * 9);
      acc = wave_reduce64(acc);
      float l2c = fmaxf(acc + b2[c2], 0.f);
      if ((lane & 1) == 0) s_pd[w * 32 + (lane >> 1)] = l2c * u;
    }
    __syncthreads();
    if (tid < 32) {
      float pdv = 0.f;
#pragma unroll
      for (int ww = 0; ww < 16; ++ww) pdv += s_pd[ww * 32 + tid];
      stg_cg1(dpart + wg * 32 + tid, pdv);
    }
    ++nb;
    gb_arrive(bar);              // S3: delta partials ready
    // S3 shadow: next step's gh (Whh@h_t), b3·innov_t, y[t+1] prefetch
    if (gru_wg && w >= 12) gh_compute();
    if (w == 0 && lane < 32) {
      int tn = (t + 1 < Tsteps) ? t + 1 : Tsteps - 1;
      yv = y[tn * Ndim + lane];
      float b = 0.f;
#pragma unroll 8
      for (int j = 0; j < 32; ++j) b = fmaf(b3[lane * 32 + j], s_innov[j], b);
      bb = b;
    }
    gb_wait(bar, nb);
  }

  // ---------------- epilogue: out row 511 ----------------
  if (wg == 0) {
    float4 a0, a1;
    ldg2_cg4(dpart + tid * 4, dpart + (tid + 1024) * 4, a0, a1);
    float4 s;
    s.x = a0.x + a1.x; s.y = a0.y + a1.y; s.z = a0.z + a1.z; s.w = a0.w + a1.w;
#pragma unroll
    for (int off = 8; off <= 32; off <<= 1) {
      s.x += __shfl_xor(s.x, off, 64);
      s.y += __shfl_xor(s.y, off, 64);
      s.z += __shfl_xor(s.z, off, 64);
      s.w += __shfl_xor(s.w, off, 64);
    }
    if (lane < 8) s_red4[w * 8 + lane] = s;
    __syncthreads();
    if (w == 0 && lane < 32) {
      float d = 0.f;
#pragma unroll
      for (int ww = 0; ww < 16; ++ww) d += s_redf[ww * 32 + lane];
      out[(Tsteps - 1) * Mdim + lane] = prior + d + bb;  // bb from last S3 shadow
    }
  }
}

extern "C" void kernel_launch(void* const* d_in, const int* in_sizes, int n_in,
                              void* d_out, int out_size, void* d_ws, size_t ws_size,
                              hipStream_t stream) {
  const float* y    = (const float*)d_in[0];
  const float* F    = (const float*)d_in[1];
  const float* Hm   = (const float*)d_in[2];
  const float* m1x0 = (const float*)d_in[3];
  const float* h0   = (const float*)d_in[4];
  const float* W1   = (const float*)d_in[5];
  const float* b1   = (const float*)d_in[6];
  const float* Wih  = (const float*)d_in[7];
  const float* bih  = (const float*)d_in[8];
  const float* Whh  = (const float*)d_in[9];
  const float* bhh  = (const float*)d_in[10];
  const float* W2   = (const float*)d_in[11];
  const float* b2   = (const float*)d_in[12];
  const float* W3   = (const float*)d_in[13];
  const float* b3   = (const float*)d_in[14];
  float* out = (float*)d_out;

  // ws layout: bar[0,4096); xb@4096 (10240B); hbuf@14336 (4000B); dpart@18432 (32768B)
  u32* bar   = (u32*)d_ws;
  u16* xb    = (u16*)((char*)d_ws + 4096);
  float* hbuf  = (float*)((char*)d_ws + 14336);
  float* dpart = (float*)((char*)d_ws + 18432);

  convert_w2<<<4000, 1024, 0, stream>>>(W2);
  convert_w3t<<<4096, 256, 0, stream>>>(W3);
  hipMemsetAsync(d_ws, 0, 4096, stream);
  hipFuncSetAttribute((const void*)knet_kernel,
                      hipFuncAttributeMaxDynamicSharedMemorySize, SMEM_BYTES);
  void* args[] = {&y, &F, &Hm, &m1x0, &h0, &W1, &b1, &Wih, &bih, &Whh, &bhh,
                  &b2, &b3, &out, &bar, &xb, &hbuf, &dpart};
  hipLaunchCooperativeKernel((const void*)knet_kernel, dim3(NWG), dim3(NTHR),
                             args, SMEM_BYTES, stream);
}

// Round 5
// 6416.523 us; speedup vs baseline: 1.7522x; 1.1623x over previous
//
#include <hip/hip_runtime.h>
#include <cmath>

#define Mdim 32
#define Ndim 32
#define Tsteps 512
#define H1dim 5120
#define H2dim 4096
#define HIDdim 1000
#define NWG 256
#define NTHR 1024
#define POLLER 320   // wave 5 lane 0: no shadow-phase duties -> dedicated barrier poller

typedef unsigned int u32;
typedef unsigned short u16;

// bf16 copies (filled by convert kernels each call)
__device__ u16 g_w2b[H2dim * HIDdim];        // [4096][1000]
__device__ u16 g_w3t[H2dim * Mdim * Ndim];   // transposed: [4096][1024]

// ---- LDS layout (bytes) ----
#define OFF_WIH 0          // 12 x 5120 bf16 = 122880
#define OFF_WHH 122880     // 12 x 1000 bf16 = 24000
#define OFF_UNION 146880   // 10240: s_x bf16[5120] | s_red4 f32x4[128] | s_pd f32[512]
#define OFF_H9 157120      // padded h: 125 chunks x 9 f32 = 4520
#define OFF_MISC 161640    // 216 floats
#define SMEM_BYTES 162560

#define MI_POST 0
#define MI_PRIOR 32
#define MI_INNOV 96
#define MI_KIN 128
#define MI_GI 192
#define MI_GH 204

__device__ __forceinline__ u16 f2bf(float f) {
  u32 u = __float_as_uint(f);
  return (u16)((u + 0x7fffu + ((u >> 16) & 1u)) >> 16);
}
__device__ __forceinline__ float bflo(u32 u) { return __uint_as_float(u << 16); }
__device__ __forceinline__ float bfhi(u32 u) { return __uint_as_float(u & 0xffff0000u); }

__device__ __forceinline__ float dot4(float4 a, float4 b) {
  return a.x * b.x + a.y * b.y + a.z * b.z + a.w * b.w;
}
__device__ __forceinline__ float dot8_bb(uint4 a, uint4 b) {
  float s = 0.f;
  s = fmaf(bflo(a.x), bflo(b.x), s); s = fmaf(bfhi(a.x), bfhi(b.x), s);
  s = fmaf(bflo(a.y), bflo(b.y), s); s = fmaf(bfhi(a.y), bfhi(b.y), s);
  s = fmaf(bflo(a.z), bflo(b.z), s); s = fmaf(bfhi(a.z), bfhi(b.z), s);
  s = fmaf(bflo(a.w), bflo(b.w), s); s = fmaf(bfhi(a.w), bfhi(b.w), s);
  return s;
}
__device__ __forceinline__ float dot8_bf(uint4 a, const float* x8) {
  float s = 0.f;
  s = fmaf(bflo(a.x), x8[0], s); s = fmaf(bfhi(a.x), x8[1], s);
  s = fmaf(bflo(a.y), x8[2], s); s = fmaf(bfhi(a.y), x8[3], s);
  s = fmaf(bflo(a.z), x8[4], s); s = fmaf(bfhi(a.z), x8[5], s);
  s = fmaf(bflo(a.w), x8[6], s); s = fmaf(bfhi(a.w), x8[7], s);
  return s;
}

__device__ __forceinline__ float wave_reduce64(float v) {
#pragma unroll
  for (int off = 32; off >= 1; off >>= 1) v += __shfl_xor(v, off, 64);
  return v;
}
__device__ __forceinline__ float group16_reduce(float v) {
#pragma unroll
  for (int off = 8; off >= 1; off >>= 1) v += __shfl_xor(v, off, 64);
  return v;
}

// ---- uncached (coherence-point) access helpers ----
__device__ __forceinline__ float4 ldg_cg4(const float* p) {
  float4 r;
  asm volatile("global_load_dwordx4 %0, %1, off sc0 sc1\n\ts_waitcnt vmcnt(0)"
               : "=v"(r) : "v"(p) : "memory");
  return r;
}
__device__ __forceinline__ uint4 ldg_cg4u(const void* p) {
  uint4 r;
  asm volatile("global_load_dwordx4 %0, %1, off sc0 sc1\n\ts_waitcnt vmcnt(0)"
               : "=v"(r) : "v"(p) : "memory");
  return r;
}
__device__ __forceinline__ void ldg2_cg4(const float* p0, const float* p1,
                                         float4& r0, float4& r1) {
  asm volatile("global_load_dwordx4 %0, %2, off sc0 sc1\n\t"
               "global_load_dwordx4 %1, %3, off sc0 sc1\n\t"
               "s_waitcnt vmcnt(0)"
               : "=&v"(r0), "=&v"(r1) : "v"(p0), "v"(p1) : "memory");
}
__device__ __forceinline__ void stg_cg1(float* p, float v) {
  asm volatile("global_store_dword %0, %1, off sc0 sc1" :: "v"(p), "v"(v) : "memory");
}
__device__ __forceinline__ void stg_cg_u16(u16* p, u16 v) {
  u32 vv = v;
  asm volatile("global_store_short %0, %1, off sc0 sc1" :: "v"(p), "v"(vv) : "memory");
}

// ---- two-level grid barrier (R0/R2-proven): 16 group counters (<=16 writers
// each) -> level-2 counter (<=16 writers, not polled) -> go line (exactly ONE
// write per barrier; pollers read it only). R4's 2-hop variant put 16 RMWs on
// the polled line and regressed 450us: polled line must have ~1 writer.
// Split arrive/wait so independent work hides under barrier latency.
__device__ __forceinline__ void gb_arrive(u32* bar) {
  asm volatile("s_waitcnt vmcnt(0)" ::: "memory");
  __syncthreads();
  if (threadIdx.x == POLLER) {
    u32 g = (u32)blockIdx.x & 15u;
    u32 a = __hip_atomic_fetch_add(bar + g * 16, 1u, __ATOMIC_RELAXED,
                                   __HIP_MEMORY_SCOPE_AGENT);
    if ((a & 15u) == 15u) {
      u32 b = __hip_atomic_fetch_add(bar + 256, 1u, __ATOMIC_RELAXED,
                                     __HIP_MEMORY_SCOPE_AGENT);
      if ((b & 15u) == 15u)
        __hip_atomic_fetch_add(bar + 320, 1u, __ATOMIC_RELAXED,
                               __HIP_MEMORY_SCOPE_AGENT);
    }
  }
}
__device__ __forceinline__ void gb_wait(u32* bar, u32 nb) {
  if (threadIdx.x == POLLER) {
    while (__hip_atomic_load(bar + 320, __ATOMIC_RELAXED,
                             __HIP_MEMORY_SCOPE_AGENT) < nb)
      __builtin_amdgcn_s_sleep(2);
  }
  __syncthreads();
}

__global__ void convert_w2(const float* __restrict__ W2) {
  int i = blockIdx.x * 1024 + threadIdx.x;
  if (i < H2dim * HIDdim) g_w2b[i] = f2bf(W2[i]);
}

__global__ void convert_w3t(const float* __restrict__ W3) {
  __shared__ float tile[32][33];
  int tr = blockIdx.x >> 7;    // 0..31
  int tc = blockIdx.x & 127;   // 0..127
  int r0 = tr * 32, c0 = tc * 32;
  int j = threadIdx.x & 31, i0 = threadIdx.x >> 5;
#pragma unroll
  for (int p = 0; p < 4; ++p) {
    int i = i0 + p * 8;
    tile[i][j] = W3[(size_t)(r0 + i) * H2dim + c0 + j];
  }
  __syncthreads();
#pragma unroll
  for (int p = 0; p < 4; ++p) {
    int i = i0 + p * 8;
    g_w3t[(size_t)(c0 + i) * 1024 + r0 + j] = f2bf(tile[j][i]);
  }
}

// NOTE: no loop-carried weight hoists. R1-R3 proved the allocator pins 64 VGPR
// for 1024-thread blocks and spills them to scratch (+20MB WRITE_SIZE).
// Weights are re-loaded in-loop (L1/L2-resident) or prefetched into
// short-lived registers inside the barrier shadows.
__global__ void __launch_bounds__(NTHR)
knet_kernel(const float* __restrict__ y, const float* __restrict__ F,
            const float* __restrict__ Hm, const float* __restrict__ m1x0,
            const float* __restrict__ h0, const float* __restrict__ W1,
            const float* __restrict__ b1, const float* __restrict__ Wih,
            const float* __restrict__ bih, const float* __restrict__ Whh,
            const float* __restrict__ bhh, const float* __restrict__ b2,
            const float* __restrict__ b3, float* __restrict__ out,
            u32* bar, u16* xb, float* hbuf, float* dpart) {
  extern __shared__ char smem[];
  u16* s_wih = (u16*)(smem + OFF_WIH);
  u16* s_whh = (u16*)(smem + OFF_WHH);
  u16* s_x = (u16*)(smem + OFF_UNION);
  float4* s_red4 = (float4*)(smem + OFF_UNION);
  float* s_redf = (float*)(smem + OFF_UNION);
  float* s_pd = (float*)(smem + OFF_UNION);
  float* s_h9 = (float*)(smem + OFF_H9);
  float* s_m = (float*)(smem + OFF_MISC);
  float* s_post = s_m + MI_POST;
  float* s_prior = s_m + MI_PRIOR;
  float* s_innov = s_m + MI_INNOV;
  float* s_kin = s_m + MI_KIN;
  float* s_gi = s_m + MI_GI;
  float* s_gh = s_m + MI_GH;

  const int tid = threadIdx.x;
  const int w = tid >> 6;
  const int lane = tid & 63;
  const int wg = blockIdx.x;
  const int k0 = wg * 4;
  const bool gru_wg = (wg < 250);
  u32 nb = 0;

  // ---------------- prologue: LDS weight staging ----------------
  if (gru_wg) {
#pragma unroll 1
    for (int r = 0; r < 12; ++r) {
      const float* src = Wih + (size_t)((r >> 2) * HIDdim + k0 + (r & 3)) * H1dim;
      u16* dst = s_wih + r * H1dim;
      for (int e = tid; e < H1dim; e += NTHR) dst[e] = f2bf(src[e]);
    }
#pragma unroll 1
    for (int r = 0; r < 12; ++r) {
      const float* src = Whh + (size_t)((r >> 2) * HIDdim + k0 + (r & 3)) * HIDdim;
      u16* dst = s_whh + r * HIDdim;
      for (int e = tid; e < HIDdim; e += NTHR) dst[e] = f2bf(src[e]);
    }
  }
  if (tid < 250) {
    float4 hv = ((const float4*)h0)[tid];
    int b0 = tid * 4;
    s_h9[((b0 + 0) >> 3) * 9 + ((b0 + 0) & 7)] = hv.x;
    s_h9[((b0 + 1) >> 3) * 9 + ((b0 + 1) & 7)] = hv.y;
    s_h9[((b0 + 2) >> 3) * 9 + ((b0 + 2) & 7)] = hv.z;
    s_h9[((b0 + 3) >> 3) * 9 + ((b0 + 3) & 7)] = hv.w;
  }
  __syncthreads();

  const int c2 = wg * 16 + w;            // this wave's W2/W3t row
  const int w1row = wg * 20 + w * 4 + (lane >> 4);  // valid for w<5
  // wave-0 persistent state: prior (lanes<32), prefetched y row, b3·innov term
  float prior = 0.f, bb = 0.f, yv = 0.f;
  if (w == 0 && lane < 32) {
    prior = m1x0[lane];
    yv = y[lane];  // y row 0
  }

  // gh: Whh @ h (needs staged s_whh/s_h9)
  auto gh_compute = [&]() {
    int base = (w - 12) * 3;
#pragma unroll
    for (int rr = 0; rr < 3; ++rr) {
      int r = base + rr;
      const uint4* wr = (const uint4*)(s_whh + r * HIDdim);
      float acc = dot8_bf(wr[lane], s_h9 + lane * 9);
      if (lane < 61) acc += dot8_bf(wr[lane + 64], s_h9 + (lane + 64) * 9);
      acc = wave_reduce64(acc);
      if (lane == 0) s_gh[r] = acc + bhh[(r >> 2) * HIDdim + k0 + (r & 3)];
    }
  };
  if (gru_wg && w >= 12) gh_compute();

  for (int t = 0; t < Tsteps; ++t) {
    // ---------------- Phase A ----------------
    if (t > 0) {  // gather delta partials: 2048 float4, 2 per thread
      float4 a0, a1;
      ldg2_cg4(dpart + tid * 4, dpart + (tid + 1024) * 4, a0, a1);
      float4 s;
      s.x = a0.x + a1.x; s.y = a0.y + a1.y; s.z = a0.z + a1.z; s.w = a0.w + a1.w;
#pragma unroll
      for (int off = 8; off <= 32; off <<= 1) {
        s.x += __shfl_xor(s.x, off, 64);
        s.y += __shfl_xor(s.y, off, 64);
        s.z += __shfl_xor(s.z, off, 64);
        s.w += __shfl_xor(s.w, off, 64);
      }
      if (lane < 8) s_red4[w * 8 + lane] = s;
    }
    __syncthreads();
    // merged serial chain, wave 0 only: no interior __syncthreads (same-wave LDS
    // is in-order; compiler-only fences stop reordering of f32 vs float4 views).
    if (w == 0) {
      float p = 0.f, inn = 0.f;
      float prev = prior;
      if (lane < 32) {
        if (t == 0) {
          p = m1x0[lane];
        } else {
          float dsum = 0.f;
#pragma unroll
          for (int ww = 0; ww < 16; ++ww) dsum += s_redf[ww * 32 + lane];
          p = prior + dsum + bb;  // bb = b3·innov computed in last S3 shadow
          if (wg == 0) out[(t - 1) * Mdim + lane] = p;
        }
        s_post[lane] = p;
      }
      asm volatile("" ::: "memory");
      if (lane < 32) {  // prior = F @ post
        const float4* Fr = (const float4*)(F + lane * Mdim);
        const float4* pp = (const float4*)s_post;
        float s = 0.f;
#pragma unroll
        for (int j = 0; j < 8; ++j) s += dot4(Fr[j], pp[j]);
        prior = s;
        s_prior[lane] = s;
      }
      asm volatile("" ::: "memory");
      if (lane < 32) {  // innov = y_t - H @ prior
        const float4* Hr = (const float4*)(Hm + lane * Mdim);
        const float4* pp = (const float4*)s_prior;
        float s = 0.f;
#pragma unroll
        for (int j = 0; j < 8; ++j) s += dot4(Hr[j], pp[j]);
        inn = yv - s;  // yv prefetched in S3 shadow
        s_innov[lane] = inn;
      }
      // kin: lanes<32 innov, lanes>=32 (post - prev_prior); normalize halves
      float vd = __shfl(p, lane & 31, 64) - __shfl(prev, lane & 31, 64);
      float v = (lane < 32) ? inn : vd;
      float sq = v * v;
#pragma unroll
      for (int off = 16; off >= 1; off >>= 1) sq += __shfl_xor(sq, off, 32);
      s_kin[lane] = v / fmaxf(sqrtf(sq), 1e-12f);
    }
    __syncthreads();
    if (w < 5) {  // x rows: 20/WG (W1 row slice is L1-resident: 5KB/WG)
      float s = dot4(((const float4*)W1)[w1row * 16 + (lane & 15)],
                     ((const float4*)s_kin)[lane & 15]);
      s = group16_reduce(s);
      if ((lane & 15) == 0) stg_cg_u16(xb + w1row, f2bf(fmaxf(s + b1[w1row], 0.f)));
    }
    ++nb;
    gb_arrive(bar);              // S1: x ready
    gb_wait(bar, nb);

    // ---------------- Phase B: gi + gates -> h ----------------
    if (gru_wg) {
      if (tid < 640) ((uint4*)s_x)[tid] = ldg_cg4u((const char*)xb + tid * 16);
      __syncthreads();
      if (w < 12) {
        const uint4* wr = (const uint4*)(s_wih + w * H1dim);
        const uint4* xr = (const uint4*)s_x;
        float acc = 0.f;
#pragma unroll
        for (int i = 0; i < 10; ++i) {
          int j = lane + 64 * i;
          acc += dot8_bb(wr[j], xr[j]);
        }
        acc = wave_reduce64(acc);
        if (lane == 0) s_gi[w] = acc + bih[(w >> 2) * HIDdim + k0 + (w & 3)];
      }
      __syncthreads();
      if (tid < 4) {
        int k = k0 + tid;
        float hold = s_h9[(k >> 3) * 9 + (k & 7)];
        float ir = s_gi[tid], iz = s_gi[4 + tid], ic = s_gi[8 + tid];
        float r = 1.f / (1.f + expf(-(ir + s_gh[tid])));
        float z = 1.f / (1.f + expf(-(iz + s_gh[4 + tid])));
        float c_ = tanhf(ic + r * s_gh[8 + tid]);
        stg_cg1(hbuf + k, (1.f - z) * c_ + z * hold);
      }
    }
    ++nb;
    gb_arrive(bar);              // S2: h ready
    // S2 shadow (short register lifetimes only — spans gb_wait, not the loop):
    //   u = W3t row · innov (independent of h), and prefetch this wave's W2 row.
    float u;
    uint4 w2a, w2b_;
    {
      const uint4* tr3 = (const uint4*)(g_w3t + (size_t)c2 * 1024);
      uint4 t0 = tr3[2 * lane], t1 = tr3[2 * lane + 1];
      const float* iv = s_innov + 16 * (lane & 1);
      u = dot8_bf(t0, iv) + dot8_bf(t1, iv + 8);
      u += __shfl_xor(u, 1, 64);
      const uint4* w2p = (const uint4*)(g_w2b + (size_t)c2 * HIDdim);
      w2a = w2p[lane];
      w2b_ = (lane < 61) ? w2p[lane + 64] : make_uint4(0u, 0u, 0u, 0u);
    }
    gb_wait(bar, nb);

    // ---------------- Phase C: l2 rows + delta partials ----------------
    if (tid < 250) {  // stage h_t (padded)
      float4 hv = ldg_cg4(hbuf + tid * 4);
      int b0 = tid * 4;
      s_h9[((b0 + 0) >> 3) * 9 + ((b0 + 0) & 7)] = hv.x;
      s_h9[((b0 + 1) >> 3) * 9 + ((b0 + 1) & 7)] = hv.y;
      s_h9[((b0 + 2) >> 3) * 9 + ((b0 + 2) & 7)] = hv.z;
      s_h9[((b0 + 3) >> 3) * 9 + ((b0 + 3) & 7)] = hv.w;
    }
    __syncthreads();
    {
      float acc = dot8_bf(w2a, s_h9 + lane * 9);
      if (lane < 61) acc += dot8_bf(w2b_, s_h9 + (lane + 64) * 9);
      acc = wave_reduce64(acc);
      float l2c = fmaxf(acc + b2[c2], 0.f);
      if ((lane & 1) == 0) s_pd[w * 32 + (lane >> 1)] = l2c * u;
    }
    __syncthreads();
    if (tid < 32) {
      float pdv = 0.f;
#pragma unroll
      for (int ww = 0; ww < 16; ++ww) pdv += s_pd[ww * 32 + tid];
      stg_cg1(dpart + wg * 32 + tid, pdv);
    }
    ++nb;
    gb_arrive(bar);              // S3: delta partials ready
    // S3 shadow: next step's gh (Whh@h_t), b3·innov_t, y[t+1] prefetch
    if (gru_wg && w >= 12) gh_compute();
    if (w == 0 && lane < 32) {
      int tn = (t + 1 < Tsteps) ? t + 1 : Tsteps - 1;
      yv = y[tn * Ndim + lane];
      float b = 0.f;
#pragma unroll 8
      for (int j = 0; j < 32; ++j) b = fmaf(b3[lane * 32 + j], s_innov[j], b);
      bb = b;
    }
    gb_wait(bar, nb);
  }

  // ---------------- epilogue: out row 511 ----------------
  if (wg == 0) {
    float4 a0, a1;
    ldg2_cg4(dpart + tid * 4, dpart + (tid + 1024) * 4, a0, a1);
    float4 s;
    s.x = a0.x + a1.x; s.y = a0.y + a1.y; s.z = a0.z + a1.z; s.w = a0.w + a1.w;
#pragma unroll
    for (int off = 8; off <= 32; off <<= 1) {
      s.x += __shfl_xor(s.x, off, 64);
      s.y += __shfl_xor(s.y, off, 64);
      s.z += __shfl_xor(s.z, off, 64);
      s.w += __shfl_xor(s.w, off, 64);
    }
    if (lane < 8) s_red4[w * 8 + lane] = s;
    __syncthreads();
    if (w == 0 && lane < 32) {
      float d = 0.f;
#pragma unroll
      for (int ww = 0; ww < 16; ++ww) d += s_redf[ww * 32 + lane];
      out[(Tsteps - 1) * Mdim + lane] = prior + d + bb;  // bb from last S3 shadow
    }
  }
}

extern "C" void kernel_launch(void* const* d_in, const int* in_sizes, int n_in,
                              void* d_out, int out_size, void* d_ws, size_t ws_size,
                              hipStream_t stream) {
  const float* y    = (const float*)d_in[0];
  const float* F    = (const float*)d_in[1];
  const float* Hm   = (const float*)d_in[2];
  const float* m1x0 = (const float*)d_in[3];
  const float* h0   = (const float*)d_in[4];
  const float* W1   = (const float*)d_in[5];
  const float* b1   = (const float*)d_in[6];
  const float* Wih  = (const float*)d_in[7];
  const float* bih  = (const float*)d_in[8];
  const float* Whh  = (const float*)d_in[9];
  const float* bhh  = (const float*)d_in[10];
  const float* W2   = (const float*)d_in[11];
  const float* b2   = (const float*)d_in[12];
  const float* W3   = (const float*)d_in[13];
  const float* b3   = (const float*)d_in[14];
  float* out = (float*)d_out;

  // ws layout: bar[0,4096); xb@4096 (10240B); hbuf@14336 (4000B); dpart@18432 (32768B)
  u32* bar   = (u32*)d_ws;
  u16* xb    = (u16*)((char*)d_ws + 4096);
  float* hbuf  = (float*)((char*)d_ws + 14336);
  float* dpart = (float*)((char*)d_ws + 18432);

  convert_w2<<<4000, 1024, 0, stream>>>(W2);
  convert_w3t<<<4096, 256, 0, stream>>>(W3);
  hipMemsetAsync(d_ws, 0, 4096, stream);
  hipFuncSetAttribute((const void*)knet_kernel,
                      hipFuncAttributeMaxDynamicSharedMemorySize, SMEM_BYTES);
  void* args[] = {&y, &F, &Hm, &m1x0, &h0, &W1, &b1, &Wih, &bih, &Whh, &bhh,
                  &b2, &b3, &out, &bar, &xb, &hbuf, &dpart};
  hipLaunchCooperativeKernel((const void*)knet_kernel, dim3(NWG), dim3(NTHR),
                             args, SMEM_BYTES, stream);
}

// Round 7
// 6385.373 us; speedup vs baseline: 1.7608x; 1.0049x over previous
//
#include <hip/hip_runtime.h>
#include <cmath>

#define Mdim 32
#define Ndim 32
#define Tsteps 512
#define H1dim 5120
#define H2dim 4096
#define HIDdim 1000
#define NWG 256
#define NTHR 1024
#define POLLER 320   // wave 5 lane 0: dedicated S3 barrier poller

typedef unsigned int u32;
typedef unsigned short u16;
typedef unsigned int u32x4 __attribute__((ext_vector_type(4)));  // true 4-VGPR tuple

// bf16 copies (filled by convert kernels each call)
__device__ u16 g_w2b[H2dim * HIDdim];        // [4096][1000]
__device__ u16 g_w3t[H2dim * Mdim * Ndim];   // transposed: [4096][1024]

// ---- LDS layout (bytes) ----
#define OFF_WIH 0          // 12 x 5120 bf16 = 122880
#define OFF_WHH 122880     // 12 x 1000 bf16 = 24000
#define OFF_UNION 146880   // 10240: s_x bf16[5120] | s_red4 f32x4[128] | s_pd f32[512]
#define OFF_H9 157120      // padded h: 125 chunks x 9 f32 = 4520
#define OFF_MISC 161640    // 216 floats
#define SMEM_BYTES 162560

#define MI_POST 0
#define MI_PRIOR 32
#define MI_INNOV 96
#define MI_KIN 128
#define MI_GI 192
#define MI_GH 204

__device__ __forceinline__ u16 f2bf(float f) {
  u32 u = __float_as_uint(f);
  return (u16)((u + 0x7fffu + ((u >> 16) & 1u)) >> 16);
}
__device__ __forceinline__ float bflo(u32 u) { return __uint_as_float(u << 16); }
__device__ __forceinline__ float bfhi(u32 u) { return __uint_as_float(u & 0xffff0000u); }

__device__ __forceinline__ float dot4(float4 a, float4 b) {
  return a.x * b.x + a.y * b.y + a.z * b.z + a.w * b.w;
}
__device__ __forceinline__ float dot8_bb(uint4 a, uint4 b) {
  float s = 0.f;
  s = fmaf(bflo(a.x), bflo(b.x), s); s = fmaf(bfhi(a.x), bfhi(b.x), s);
  s = fmaf(bflo(a.y), bflo(b.y), s); s = fmaf(bfhi(a.y), bfhi(b.y), s);
  s = fmaf(bflo(a.z), bflo(b.z), s); s = fmaf(bfhi(a.z), bfhi(b.z), s);
  s = fmaf(bflo(a.w), bflo(b.w), s); s = fmaf(bfhi(a.w), bfhi(b.w), s);
  return s;
}
__device__ __forceinline__ float dot8_bf(uint4 a, const float* x8) {
  float s = 0.f;
  s = fmaf(bflo(a.x), x8[0], s); s = fmaf(bfhi(a.x), x8[1], s);
  s = fmaf(bflo(a.y), x8[2], s); s = fmaf(bfhi(a.y), x8[3], s);
  s = fmaf(bflo(a.z), x8[4], s); s = fmaf(bfhi(a.z), x8[5], s);
  s = fmaf(bflo(a.w), x8[6], s); s = fmaf(bfhi(a.w), x8[7], s);
  return s;
}

__device__ __forceinline__ float wave_reduce64(float v) {
#pragma unroll
  for (int off = 32; off >= 1; off >>= 1) v += __shfl_xor(v, off, 64);
  return v;
}

// ---- uncached (coherence-point) access helpers ----
__device__ __forceinline__ uint4 ldg_cg4u(const void* p) {
  uint4 r;
  asm volatile("global_load_dwordx4 %0, %1, off sc0 sc1\n\ts_waitcnt vmcnt(0)"
               : "=v"(r) : "v"(p) : "memory");
  return r;
}
__device__ __forceinline__ void ldg2_cg4(const float* p0, const float* p1,
                                         float4& r0, float4& r1) {
  asm volatile("global_load_dwordx4 %0, %2, off sc0 sc1\n\t"
               "global_load_dwordx4 %1, %3, off sc0 sc1\n\t"
               "s_waitcnt vmcnt(0)"
               : "=&v"(r0), "=&v"(r1) : "v"(p0), "v"(p1) : "memory");
}
__device__ __forceinline__ void stg_cg1(float* p, float v) {
  asm volatile("global_store_dword %0, %1, off sc0 sc1" :: "v"(p), "v"(v) : "memory");
}
__device__ __forceinline__ void stg_cg4u(void* p, u32 a, u32 b, u32 c, u32 d) {
  u32x4 v; v.x = a; v.y = b; v.z = c; v.w = d;   // ext_vector: valid "v" input
  asm volatile("global_store_dwordx4 %0, %1, off sc0 sc1" :: "v"(p), "v"(v) : "memory");
}

// ---- two-level grid barrier (R5-proven): 16 group counters (<=16 writers each)
// -> level-2 counter -> go line (ONE write per barrier; pollers read only).
__device__ __forceinline__ void gb_arrive(u32* bar) {
  asm volatile("s_waitcnt vmcnt(0)" ::: "memory");
  __syncthreads();
  if (threadIdx.x == POLLER) {
    u32 g = (u32)blockIdx.x & 15u;
    u32 a = __hip_atomic_fetch_add(bar + g * 16, 1u, __ATOMIC_RELAXED,
                                   __HIP_MEMORY_SCOPE_AGENT);
    if ((a & 15u) == 15u) {
      u32 b = __hip_atomic_fetch_add(bar + 256, 1u, __ATOMIC_RELAXED,
                                     __HIP_MEMORY_SCOPE_AGENT);
      if ((b & 15u) == 15u)
        __hip_atomic_fetch_add(bar + 320, 1u, __ATOMIC_RELAXED,
                               __HIP_MEMORY_SCOPE_AGENT);
    }
  }
}
__device__ __forceinline__ void gb_wait(u32* bar, u32 nb) {
  if (threadIdx.x == POLLER) {
    while (__hip_atomic_load(bar + 320, __ATOMIC_RELAXED,
                             __HIP_MEMORY_SCOPE_AGENT) < nb)
      __builtin_amdgcn_s_sleep(2);
  }
  __syncthreads();
}

__global__ void convert_w2(const float* __restrict__ W2) {
  int i = blockIdx.x * 1024 + threadIdx.x;
  if (i < H2dim * HIDdim) g_w2b[i] = f2bf(W2[i]);
}

__global__ void convert_w3t(const float* __restrict__ W3) {
  __shared__ float tile[32][33];
  int tr = blockIdx.x >> 7;    // 0..31
  int tc = blockIdx.x & 127;   // 0..127
  int r0 = tr * 32, c0 = tc * 32;
  int j = threadIdx.x & 31, i0 = threadIdx.x >> 5;
#pragma unroll
  for (int p = 0; p < 4; ++p) {
    int i = i0 + p * 8;
    tile[i][j] = W3[(size_t)(r0 + i) * H2dim + c0 + j];
  }
  __syncthreads();
#pragma unroll
  for (int p = 0; p < 4; ++p) {
    int i = i0 + p * 8;
    g_w3t[(size_t)(c0 + i) * 1024 + r0 + j] = f2bf(tile[j][i]);
  }
}

// Dataflow exchange for x and h (tag = t+1 packed in the same 16B store as the
// data -> single-transaction publish, no ordering hazard). The single S3
// barrier per step prevents cross-step overwrite (single-buffered, no ABA).
// x format : 3 groups/WG, {7 bf16, u16 tag} per 16B group (group 2: 6 valid).
// h format : 1000 groups, {f32 h, u32 tag, 0, 0} per 16B group.
__global__ void __launch_bounds__(NTHR)
knet_kernel(const float* __restrict__ y, const float* __restrict__ F,
            const float* __restrict__ Hm, const float* __restrict__ m1x0,
            const float* __restrict__ h0, const float* __restrict__ W1,
            const float* __restrict__ b1, const float* __restrict__ Wih,
            const float* __restrict__ bih, const float* __restrict__ Whh,
            const float* __restrict__ bhh, const float* __restrict__ b2,
            const float* __restrict__ b3, float* __restrict__ out,
            u32* bar, u32* xbt, u32* hbt, float* dpart) {
  extern __shared__ char smem[];
  u16* s_wih = (u16*)(smem + OFF_WIH);
  u16* s_whh = (u16*)(smem + OFF_WHH);
  u16* s_x = (u16*)(smem + OFF_UNION);
  float4* s_red4 = (float4*)(smem + OFF_UNION);
  float* s_redf = (float*)(smem + OFF_UNION);
  float* s_pd = (float*)(smem + OFF_UNION);
  float* s_h9 = (float*)(smem + OFF_H9);
  float* s_m = (float*)(smem + OFF_MISC);
  float* s_post = s_m + MI_POST;
  float* s_prior = s_m + MI_PRIOR;
  float* s_innov = s_m + MI_INNOV;
  float* s_kin = s_m + MI_KIN;
  float* s_gi = s_m + MI_GI;
  float* s_gh = s_m + MI_GH;

  const int tid = threadIdx.x;
  const int w = tid >> 6;
  const int lane = tid & 63;
  const int wg = blockIdx.x;
  const int k0 = wg * 4;
  const bool gru_wg = (wg < 250);
  u32 nb = 0;

  // ---------------- prologue: LDS weight staging ----------------
  if (gru_wg) {
#pragma unroll 1
    for (int r = 0; r < 12; ++r) {
      const float* src = Wih + (size_t)((r >> 2) * HIDdim + k0 + (r & 3)) * H1dim;
      u16* dst = s_wih + r * H1dim;
      for (int e = tid; e < H1dim; e += NTHR) dst[e] = f2bf(src[e]);
    }
#pragma unroll 1
    for (int r = 0; r < 12; ++r) {
      const float* src = Whh + (size_t)((r >> 2) * HIDdim + k0 + (r & 3)) * HIDdim;
      u16* dst = s_whh + r * HIDdim;
      for (int e = tid; e < HIDdim; e += NTHR) dst[e] = f2bf(src[e]);
    }
  }
  if (tid < 250) {
    float4 hv = ((const float4*)h0)[tid];
    int b0 = tid * 4;
    s_h9[((b0 + 0) >> 3) * 9 + ((b0 + 0) & 7)] = hv.x;
    s_h9[((b0 + 1) >> 3) * 9 + ((b0 + 1) & 7)] = hv.y;
    s_h9[((b0 + 2) >> 3) * 9 + ((b0 + 2) & 7)] = hv.z;
    s_h9[((b0 + 3) >> 3) * 9 + ((b0 + 3) & 7)] = hv.w;
  }
  __syncthreads();

  const int c2 = wg * 16 + w;            // this wave's W2/W3t row
  // wave-0 persistent state: prior (lanes<32), prefetched y row, b3·innov term
  float prior = 0.f, bb = 0.f, yv = 0.f;
  if (w == 0 && lane < 32) {
    prior = m1x0[lane];
    yv = y[lane];  // y row 0
  }

  // gh: Whh @ h (needs staged s_whh/s_h9)
  auto gh_compute = [&]() {
    int base = (w - 12) * 3;
#pragma unroll
    for (int rr = 0; rr < 3; ++rr) {
      int r = base + rr;
      const uint4* wr = (const uint4*)(s_whh + r * HIDdim);
      float acc = dot8_bf(wr[lane], s_h9 + lane * 9);
      if (lane < 61) acc += dot8_bf(wr[lane + 64], s_h9 + (lane + 64) * 9);
      acc = wave_reduce64(acc);
      if (lane == 0) s_gh[r] = acc + bhh[(r >> 2) * HIDdim + k0 + (r & 3)];
    }
  };
  if (gru_wg && w >= 12) gh_compute();

  for (int t = 0; t < Tsteps; ++t) {
    const u32 want = (u32)(t + 1);
    // ---------------- Phase A ----------------
    if (t > 0) {  // gather delta partials: 2048 float4, 2 per thread
      float4 a0, a1;
      ldg2_cg4(dpart + tid * 4, dpart + (tid + 1024) * 4, a0, a1);
      float4 s;
      s.x = a0.x + a1.x; s.y = a0.y + a1.y; s.z = a0.z + a1.z; s.w = a0.w + a1.w;
#pragma unroll
      for (int off = 8; off <= 32; off <<= 1) {
        s.x += __shfl_xor(s.x, off, 64);
        s.y += __shfl_xor(s.y, off, 64);
        s.z += __shfl_xor(s.z, off, 64);
        s.w += __shfl_xor(s.w, off, 64);
      }
      if (lane < 8) s_red4[w * 8 + lane] = s;
    }
    __syncthreads();
    // merged serial chain, wave 0 only (no interior __syncthreads; same-wave LDS
    // is in-order; compiler-only fences stop f32/float4 view reordering).
    if (w == 0) {
      float p = 0.f, inn = 0.f;
      float prev = prior;
      if (lane < 32) {
        if (t == 0) {
          p = m1x0[lane];
        } else {
          float dsum = 0.f;
#pragma unroll
          for (int ww = 0; ww < 16; ++ww) dsum += s_redf[ww * 32 + lane];
          p = prior + dsum + bb;  // bb = b3·innov from last S3 shadow
          if (wg == 0) out[(t - 1) * Mdim + lane] = p;
        }
        s_post[lane] = p;
      }
      asm volatile("" ::: "memory");
      if (lane < 32) {  // prior = F @ post
        const float4* Fr = (const float4*)(F + lane * Mdim);
        const float4* pp = (const float4*)s_post;
        float s = 0.f;
#pragma unroll
        for (int j = 0; j < 8; ++j) s += dot4(Fr[j], pp[j]);
        prior = s;
        s_prior[lane] = s;
      }
      asm volatile("" ::: "memory");
      if (lane < 32) {  // innov = y_t - H @ prior
        const float4* Hr = (const float4*)(Hm + lane * Mdim);
        const float4* pp = (const float4*)s_prior;
        float s = 0.f;
#pragma unroll
        for (int j = 0; j < 8; ++j) s += dot4(Hr[j], pp[j]);
        inn = yv - s;
        s_innov[lane] = inn;
      }
      // kin: lanes<32 innov, lanes>=32 (post - prev_prior); normalize halves
      float vd = __shfl(p, lane & 31, 64) - __shfl(prev, lane & 31, 64);
      float v = (lane < 32) ? inn : vd;
      float sq = v * v;
#pragma unroll
      for (int off = 16; off >= 1; off >>= 1) sq += __shfl_xor(sq, off, 32);
      s_kin[lane] = v / fmaxf(sqrtf(sq), 1e-12f);
    }
    __syncthreads();   // publish s_innov (wave 0 continues: W1 + x publish)

    // ---- wave 0: W1 rows (3 lanes/row) -> pack -> tagged x store ----
    if (w == 0) {
      int r = lane / 3;
      int p = lane - r * 3;
      float acc = 0.f;
      if (r < 20) {
        const float4* Wr = (const float4*)W1 + (size_t)(wg * 20 + r) * 16;
        const float4* kc = (const float4*)s_kin;
#pragma unroll
        for (int c = p; c < 16; c += 3) acc += dot4(Wr[c], kc[c]);
      }
      int rr = (r < 20) ? r : 0;
      float a1v = __shfl(acc, rr * 3 + 1, 64);
      float a2v = __shfl(acc, rr * 3 + 2, 64);
      u32 myval = 0;
      if (r < 20 && p == 0)
        myval = (u32)f2bf(fmaxf(acc + a1v + a2v + b1[wg * 20 + r], 0.f));
      u32 vs[7];
      int q = (lane < 3) ? lane : 0;
#pragma unroll
      for (int s2 = 0; s2 < 7; ++s2) {
        int ridx = q * 7 + s2;
        vs[s2] = __shfl(myval, (ridx < 20 ? ridx : 0) * 3, 64);
      }
      if (lane < 3) {
        stg_cg4u((char*)xbt + (size_t)(wg * 3 + lane) * 16,
                 vs[0] | (vs[1] << 16),
                 vs[2] | (vs[3] << 16),
                 vs[4] | (vs[5] << 16),
                 ((lane == 2) ? 0u : vs[6]) | (want << 16));
      }
    }
    // ---- all waves: u = W3t row · innov, W2 row prefetch (h-independent) ----
    float u;
    uint4 w2a, w2b_;
    {
      const uint4* tr3 = (const uint4*)(g_w3t + (size_t)c2 * 1024);
      uint4 t0 = tr3[2 * lane], t1 = tr3[2 * lane + 1];
      const float* iv = s_innov + 16 * (lane & 1);
      u = dot8_bf(t0, iv) + dot8_bf(t1, iv + 8);
      u += __shfl_xor(u, 1, 64);
      const uint4* w2p = (const uint4*)(g_w2b + (size_t)c2 * HIDdim);
      w2a = w2p[lane];
      w2b_ = (lane < 61) ? w2p[lane + 64] : make_uint4(0u, 0u, 0u, 0u);
    }
    // ---- x poll+stage: gru WGs, waves 4-15 own one group each ----
    if (gru_wg && tid >= 256) {
      int g = tid - 256;
      int swg = g / 3;
      int q = g - swg * 3;
      const char* gp = (const char*)xbt + (size_t)g * 16;
      uint4 v;
      for (;;) {
        v = ldg_cg4u(gp);
        if ((v.w >> 16) == want) break;
        __builtin_amdgcn_s_sleep(1);
      }
      u16* sx = (u16*)s_x;
      int base = swg * 20 + q * 7;
      sx[base + 0] = (u16)(v.x & 0xffff);
      sx[base + 1] = (u16)(v.x >> 16);
      sx[base + 2] = (u16)(v.y & 0xffff);
      sx[base + 3] = (u16)(v.y >> 16);
      sx[base + 4] = (u16)(v.z & 0xffff);
      sx[base + 5] = (u16)(v.z >> 16);
      if (q != 2) sx[base + 6] = (u16)(v.w & 0xffff);
    }
    __syncthreads();   // s_x ready

    // ---------------- gi: waves 0-11 ----------------
    if (gru_wg && w < 12) {
      const uint4* wr = (const uint4*)(s_wih + w * H1dim);
      const uint4* xr = (const uint4*)s_x;
      float acc = 0.f;
#pragma unroll
      for (int i = 0; i < 10; ++i) {
        int j = lane + 64 * i;
        acc += dot8_bb(wr[j], xr[j]);
      }
      acc = wave_reduce64(acc);
      if (lane == 0) s_gi[w] = acc + bih[(w >> 2) * HIDdim + k0 + (w & 3)];
    }
    __syncthreads();   // s_gi ready

    // ---- gates -> tagged h store (wave 0 lanes 0-3; reads OLD s_h9 first) ----
    if (gru_wg && w == 0 && lane < 4) {
      int k = k0 + lane;
      float hold = s_h9[(k >> 3) * 9 + (k & 7)];
      float ir = s_gi[lane], iz = s_gi[4 + lane], ic = s_gi[8 + lane];
      float r = 1.f / (1.f + expf(-(ir + s_gh[lane])));
      float z = 1.f / (1.f + expf(-(iz + s_gh[4 + lane])));
      float c_ = tanhf(ic + r * s_gh[8 + lane]);
      float hv = (1.f - z) * c_ + z * hold;
      stg_cg4u((char*)hbt + (size_t)k * 16, __float_as_uint(hv), want, 0u, 0u);
    }
    // ---- h poll+stage: all WGs, one group per thread ----
    if (tid < HIDdim) {
      const char* gp = (const char*)hbt + (size_t)tid * 16;
      uint4 v;
      for (;;) {
        v = ldg_cg4u(gp);
        if (v.y == want) break;
        __builtin_amdgcn_s_sleep(1);
      }
      s_h9[(tid >> 3) * 9 + (tid & 7)] = __uint_as_float(v.x);
    }
    __syncthreads();   // s_h9 = h_t

    // ---------------- Phase C: l2 rows + delta partials ----------------
    {
      float acc = dot8_bf(w2a, s_h9 + lane * 9);
      if (lane < 61) acc += dot8_bf(w2b_, s_h9 + (lane + 64) * 9);
      acc = wave_reduce64(acc);
      float l2c = fmaxf(acc + b2[c2], 0.f);
      if ((lane & 1) == 0) s_pd[w * 32 + (lane >> 1)] = l2c * u;
    }
    __syncthreads();
    if (tid < 32) {
      float pdv = 0.f;
#pragma unroll
      for (int ww = 0; ww < 16; ++ww) pdv += s_pd[ww * 32 + tid];
      stg_cg1(dpart + wg * 32 + tid, pdv);
    }
    ++nb;
    gb_arrive(bar);              // S3: delta partials ready (sole barrier)
    // S3 shadow: next step's gh (Whh@h_t), b3·innov_t, y[t+1] prefetch
    if (gru_wg && w >= 12) gh_compute();
    if (w == 0 && lane < 32) {
      int tn = (t + 1 < Tsteps) ? t + 1 : Tsteps - 1;
      yv = y[tn * Ndim + lane];
      float b = 0.f;
#pragma unroll 8
      for (int j = 0; j < 32; ++j) b = fmaf(b3[lane * 32 + j], s_innov[j], b);
      bb = b;
    }
    gb_wait(bar, nb);
  }

  // ---------------- epilogue: out row 511 ----------------
  if (wg == 0) {
    float4 a0, a1;
    ldg2_cg4(dpart + tid * 4, dpart + (tid + 1024) * 4, a0, a1);
    float4 s;
    s.x = a0.x + a1.x; s.y = a0.y + a1.y; s.z = a0.z + a1.z; s.w = a0.w + a1.w;
#pragma unroll
    for (int off = 8; off <= 32; off <<= 1) {
      s.x += __shfl_xor(s.x, off, 64);
      s.y += __shfl_xor(s.y, off, 64);
      s.z += __shfl_xor(s.z, off, 64);
      s.w += __shfl_xor(s.w, off, 64);
    }
    if (lane < 8) s_red4[w * 8 + lane] = s;
    __syncthreads();
    if (w == 0 && lane < 32) {
      float d = 0.f;
#pragma unroll
      for (int ww = 0; ww < 16; ++ww) d += s_redf[ww * 32 + lane];
      out[(Tsteps - 1) * Mdim + lane] = prior + d + bb;  // bb from last S3 shadow
    }
  }
}

extern "C" void kernel_launch(void* const* d_in, const int* in_sizes, int n_in,
                              void* d_out, int out_size, void* d_ws, size_t ws_size,
                              hipStream_t stream) {
  const float* y    = (const float*)d_in[0];
  const float* F    = (const float*)d_in[1];
  const float* Hm   = (const float*)d_in[2];
  const float* m1x0 = (const float*)d_in[3];
  const float* h0   = (const float*)d_in[4];
  const float* W1   = (const float*)d_in[5];
  const float* b1   = (const float*)d_in[6];
  const float* Wih  = (const float*)d_in[7];
  const float* bih  = (const float*)d_in[8];
  const float* Whh  = (const float*)d_in[9];
  const float* bhh  = (const float*)d_in[10];
  const float* W2   = (const float*)d_in[11];
  const float* b2   = (const float*)d_in[12];
  const float* W3   = (const float*)d_in[13];
  const float* b3   = (const float*)d_in[14];
  float* out = (float*)d_out;

  // ws layout: bar[0,4096); xbt[4096,16384) 768x16B; hbt[16384,32768) 1000x16B;
  // dpart[32768,65536). memset zeroes bar + all tags each launch.
  u32* bar   = (u32*)d_ws;
  u32* xbt   = (u32*)((char*)d_ws + 4096);
  u32* hbt   = (u32*)((char*)d_ws + 16384);
  float* dpart = (float*)((char*)d_ws + 32768);

  convert_w2<<<4000, 1024, 0, stream>>>(W2);
  convert_w3t<<<4096, 256, 0, stream>>>(W3);
  hipMemsetAsync(d_ws, 0, 32768, stream);
  hipFuncSetAttribute((const void*)knet_kernel,
                      hipFuncAttributeMaxDynamicSharedMemorySize, SMEM_BYTES);
  void* args[] = {&y, &F, &Hm, &m1x0, &h0, &W1, &b1, &Wih, &bih, &Whh, &bhh,
                  &b2, &b3, &out, &bar, &xbt, &hbt, &dpart};
  hipLaunchCooperativeKernel((const void*)knet_kernel, dim3(NWG), dim3(NTHR),
                             args, SMEM_BYTES, stream);
}